// Round 1
// baseline (408.125 us; speedup 1.0000x reference)
//
#include <hip/hip_runtime.h>

// x:    (2, 768, 8,8,8)   -> (2,768,512)
// out:  (2, 48, 64,64,64) -> (2,48,262144)
// output: (2, 32, 64,64,64)
constexpr int NCLS = 32;

// ws float offsets
constexpr int WS_POOL = 64;     // 2*768
constexpr int WS_XF  = 1600;    // 2*256
constexpr int WS_PAR = 2112;    // 2*32*153 = 9792
constexpr int WS_P2  = 11904;   // 768 blocks * {sum,sumsq}

__device__ __forceinline__ float wred(float v) {
#pragma unroll
  for (int off = 32; off > 0; off >>= 1) v += __shfl_down(v, off, 64);
  return v;
}

__device__ __forceinline__ float4 fma4(float w, float4 v, float4 a) {
  a.x = fmaf(w, v.x, a.x); a.y = fmaf(w, v.y, a.y);
  a.z = fmaf(w, v.z, a.z); a.w = fmaf(w, v.w, a.w);
  return a;
}
__device__ __forceinline__ float4 relu4(float4 a) {
  a.x = fmaxf(a.x, 0.f); a.y = fmaxf(a.y, 0.f);
  a.z = fmaxf(a.z, 0.f); a.w = fmaxf(a.w, 0.f);
  return a;
}
__device__ __forceinline__ float4 bcast4(float v) { return make_float4(v, v, v, v); }

// K1: 800 blocks. Blocks 0..767: GN2 partial sums (32768 contiguous floats each).
//     Blocks 768..799: GN1 stats + relu-mean pool for one (b,group) (24576 floats).
__global__ void k1_stats(const float* __restrict__ x, const float* __restrict__ oin,
                         const float* __restrict__ g1, const float* __restrict__ b1,
                         float* __restrict__ ws) {
  int t = threadIdx.x;
  int wid = t >> 6, lane = t & 63;
  __shared__ float red[8];
  if (blockIdx.x < 768) {
    int blk = blockIdx.x;
    const float4* p = reinterpret_cast<const float4*>(oin + (size_t)blk * 32768);
    float s = 0.f, s2 = 0.f;
#pragma unroll
    for (int k = 0; k < 32; ++k) {
      float4 v = p[k * 256 + t];
      s  += v.x + v.y + v.z + v.w;
      s2 += v.x*v.x + v.y*v.y + v.z*v.z + v.w*v.w;
    }
    s = wred(s); s2 = wred(s2);
    if (lane == 0) { red[wid*2] = s; red[wid*2+1] = s2; }
    __syncthreads();
    if (t == 0) {
      ws[WS_P2 + blk*2]   = red[0]+red[2]+red[4]+red[6];
      ws[WS_P2 + blk*2+1] = red[1]+red[3]+red[5]+red[7];
    }
  } else {
    int g = blockIdx.x - 768;              // b = g>>4, grp = g&15
    __shared__ float mstat[2];
    const float4* p = reinterpret_cast<const float4*>(x + g * 24576);
    float s = 0.f, s2 = 0.f;
#pragma unroll
    for (int k = 0; k < 24; ++k) {
      float4 v = p[k * 256 + t];
      s  += v.x + v.y + v.z + v.w;
      s2 += v.x*v.x + v.y*v.y + v.z*v.z + v.w*v.w;
    }
    s = wred(s); s2 = wred(s2);
    if (lane == 0) { red[wid*2] = s; red[wid*2+1] = s2; }
    __syncthreads();
    if (t == 0) {
      float S  = red[0]+red[2]+red[4]+red[6];
      float S2 = red[1]+red[3]+red[5]+red[7];
      float mean = S * (1.f/24576.f);
      float var  = S2 * (1.f/24576.f) - mean*mean;
      mstat[0] = mean; mstat[1] = rsqrtf(var + 1e-5f);
    }
    __syncthreads();
    float mean = mstat[0], rstd = mstat[1];
#pragma unroll
    for (int k = 0; k < 12; ++k) {
      int i = k*4 + wid;                   // channel within group [0,48)
      int c = (g & 15) * 48 + i;           // channel [0,768)
      float sc = rstd * g1[c];
      float sh = b1[c] - mean * sc;
      const float* q = x + g * 24576 + i * 512;
      float acc = 0.f;
#pragma unroll
      for (int j = 0; j < 8; ++j)
        acc += fmaxf(fmaf(q[lane + j*64], sc, sh), 0.f);
      acc = wred(acc);
      if (lane == 0) ws[WS_POOL + (g >> 4) * 768 + c] = acc * (1.f/512.f);
    }
  }
}

// K2: x_feat, wave-per-output (coalesced row reads). 512 outputs -> 128 blocks.
__global__ void k2_xfeat(const float* __restrict__ gapw, const float* __restrict__ gapb,
                         float* __restrict__ ws) {
  int wid = threadIdx.x >> 6, lane = threadIdx.x & 63;
  int idx = blockIdx.x * 4 + wid;          // [0,512)
  int b = idx >> 8, o = idx & 255;
  const float* pw = gapw + o * 768;
  const float* pp = ws + WS_POOL + b * 768;
  float s = 0.f;
#pragma unroll
  for (int i = 0; i < 12; ++i) {
    int cc = lane + i*64;
    s += pw[cc] * pp[cc];
  }
  s = wred(s);
  if (lane == 0) ws[WS_XF + idx] = s + gapb[o];
}

// K3: params, wave-per-output (coalesced). 9792 outputs -> 2448 blocks.
__global__ void k3_params(const float* __restrict__ cw, const float* __restrict__ cb,
                          const float* __restrict__ te, float* __restrict__ ws) {
  int wid = threadIdx.x >> 6, lane = threadIdx.x & 63;
  int e = blockIdx.x * 4 + wid;            // [0,9792)
  int b = e / (NCLS * 153);
  int r = e % (NCLS * 153);
  int c = r / 153, p = r % 153;
  const float* w  = cw + p * 512;
  const float* xf = ws + WS_XF + b * 256;
  const float* tv = te + c * 256;
  float s = 0.f;
#pragma unroll
  for (int i = 0; i < 4; ++i) {
    int f = lane + i*64;
    s += w[f] * xf[f] + w[256 + f] * tv[f];
  }
  s = wred(s);
  if (lane == 0) ws[WS_PAR + e] = s + cb[p];
}

// K4: fused GN2-finalize + main head.
// Occupancy-oriented layout: 1024 blocks x 256 thr; thread = 4 voxels (1 float4).
// Classes split 16/16 across paired blocks (adjacent blockIdx -> shared oin tile in L2/L3).
// __launch_bounds__(256,4): VGPR<=128 -> 4 waves/SIMD, matching 4 blocks/CU from the grid.
__global__ __launch_bounds__(256, 4) void k4_main(const float* __restrict__ oin,
                                                  const float* __restrict__ prew,
                                                  const float* __restrict__ preb,
                                                  const float* __restrict__ g2,
                                                  const float* __restrict__ b2,
                                                  const float* __restrict__ ws,
                                                  float* __restrict__ out) {
  __shared__ __align__(16) float Wl[16 * 160];   // 16 classes, 160-float stride
  __shared__ __align__(16) float prewT[384];
  __shared__ float2 ssl[48];
  __shared__ float ms[64];
  int t = threadIdx.x;
  int b    = blockIdx.x >> 9;        // batch [0,2)
  int rem  = blockIdx.x & 511;
  int tile = rem >> 1;               // [0,256) -> 1024 floats per channel
  int cls0 = (rem & 1) << 4;         // 0 or 16

  if (t < 32) {
    float S = 0.f, S2 = 0.f;
#pragma unroll
    for (int k = 0; k < 24; ++k) {
      S  += ws[WS_P2 + (t*24 + k)*2];
      S2 += ws[WS_P2 + (t*24 + k)*2 + 1];
    }
    float mean = S * (1.f/786432.f);
    float var  = S2 * (1.f/786432.f) - mean*mean;
    ms[t*2] = mean; ms[t*2+1] = rsqrtf(var + 1e-5f);
  }
  if (t < 128) {
#pragma unroll
    for (int k = 0; k < 3; ++k) {
      int i = t + k*128;
      prewT[(i % 48) * 8 + (i / 48)] = prew[i];
    }
  }
  {
    const float* wsrc = ws + WS_PAR + (b * NCLS + cls0) * 153;
#pragma unroll 4
    for (int cc = 0; cc < 16; ++cc)
      if (t < 153) Wl[cc*160 + t] = wsrc[cc*153 + t];
  }
  __syncthreads();
  if (t < 48) {
    int grp = (b << 4) + t / 3;
    float mean = ms[grp*2], rstd = ms[grp*2+1];
    float sc = rstd * g2[t];
    ssl[t] = make_float2(sc, b2[t] - mean * sc);
  }
  __syncthreads();

  // h0 for 4 voxels (one float4)
  const float4* ip4 = reinterpret_cast<const float4*>(oin)
                      + (size_t)b * 48 * 65536 + tile*256 + t;
  const float4* pT4 = reinterpret_cast<const float4*>(prewT);
  float4 h0[8];
#pragma unroll
  for (int o = 0; o < 8; ++o) h0[o] = bcast4(preb[o]);
#pragma unroll 8
  for (int c = 0; c < 48; ++c) {
    float4 v = ip4[(size_t)c * 65536];
    float2 ss = ssl[c];
    float4 g = relu4(make_float4(fmaf(v.x, ss.x, ss.y), fmaf(v.y, ss.x, ss.y),
                                 fmaf(v.z, ss.x, ss.y), fmaf(v.w, ss.x, ss.y)));
    float4 w0 = pT4[c*2], w1 = pT4[c*2+1];
    h0[0] = fma4(w0.x, g, h0[0]);
    h0[1] = fma4(w0.y, g, h0[1]);
    h0[2] = fma4(w0.z, g, h0[2]);
    h0[3] = fma4(w0.w, g, h0[3]);
    h0[4] = fma4(w1.x, g, h0[4]);
    h0[5] = fma4(w1.y, g, h0[5]);
    h0[6] = fma4(w1.z, g, h0[6]);
    h0[7] = fma4(w1.w, g, h0[7]);
  }

  float4* op4 = reinterpret_cast<float4*>(out)
                + (size_t)(b * NCLS + cls0) * 65536 + tile*256 + t;
#pragma unroll 1
  for (int cls = 0; cls < 16; ++cls) {
    const float*  Wc = Wl + cls * 160;
    const float4* W4 = reinterpret_cast<const float4*>(Wc);
    // layer1: t1 = relu(w1 @ h0 + b1)
    float4 t1[8];
#pragma unroll
    for (int i = 0; i < 8; ++i) {
      float4 w0 = W4[i*2], w1 = W4[i*2+1];
      float4 a = bcast4(Wc[136 + i]);          // b1[i] broadcast from LDS
      a = fma4(w0.x, h0[0], a);
      a = fma4(w0.y, h0[1], a);
      a = fma4(w0.z, h0[2], a);
      a = fma4(w0.w, h0[3], a);
      a = fma4(w1.x, h0[4], a);
      a = fma4(w1.y, h0[5], a);
      a = fma4(w1.z, h0[6], a);
      a = fma4(w1.w, h0[7], a);
      t1[i] = relu4(a);
    }
    // layer2 + layer3 fused (t2 row consumed immediately)
    float4 w3q0 = W4[32], w3q1 = W4[33];
    float w3arr[8] = {w3q0.x,w3q0.y,w3q0.z,w3q0.w,w3q1.x,w3q1.y,w3q1.z,w3q1.w};
    float4 lg = bcast4(Wc[152]);               // b3
#pragma unroll
    for (int i = 0; i < 8; ++i) {
      float4 w0 = W4[16 + i*2], w1 = W4[17 + i*2];
      float4 a = bcast4(Wc[144 + i]);          // b2[i]
      a = fma4(w0.x, t1[0], a);
      a = fma4(w0.y, t1[1], a);
      a = fma4(w0.z, t1[2], a);
      a = fma4(w0.w, t1[3], a);
      a = fma4(w1.x, t1[4], a);
      a = fma4(w1.y, t1[5], a);
      a = fma4(w1.z, t1[6], a);
      a = fma4(w1.w, t1[7], a);
      a = relu4(a);
      lg = fma4(w3arr[i], a, lg);
    }
    op4[(size_t)cls * 65536] = lg;
  }
}

extern "C" void kernel_launch(void* const* d_in, const int* in_sizes, int n_in,
                              void* d_out, int out_size, void* d_ws, size_t ws_size,
                              hipStream_t stream) {
  const float* x    = (const float*)d_in[0];
  const float* oin  = (const float*)d_in[1];
  const float* te   = (const float*)d_in[2];
  const float* g1   = (const float*)d_in[3];
  const float* b1   = (const float*)d_in[4];
  const float* gapw = (const float*)d_in[5];
  const float* gapb = (const float*)d_in[6];
  const float* cw   = (const float*)d_in[7];
  const float* cb   = (const float*)d_in[8];
  const float* g2   = (const float*)d_in[9];
  const float* b2   = (const float*)d_in[10];
  const float* prew = (const float*)d_in[11];
  const float* preb = (const float*)d_in[12];
  float* ws  = (float*)d_ws;
  float* out = (float*)d_out;

  hipLaunchKernelGGL(k1_stats,  dim3(800),  dim3(256), 0, stream, x, oin, g1, b1, ws);
  hipLaunchKernelGGL(k2_xfeat,  dim3(128),  dim3(256), 0, stream, gapw, gapb, ws);
  hipLaunchKernelGGL(k3_params, dim3(2448), dim3(256), 0, stream, cw, cb, te, ws);
  hipLaunchKernelGGL(k4_main,   dim3(1024), dim3(256), 0, stream, oin, prew, preb, g2, b2, ws, out);
}

// Round 2
// 332.189 us; speedup vs baseline: 1.2286x; 1.2286x over previous
//
#include <hip/hip_runtime.h>

// x:    (2, 768, 8,8,8)   -> (2,768,512)
// out:  (2, 48, 64,64,64) -> (2,48,262144)
// output: (2, 32, 64,64,64)
constexpr int NCLS = 32;

// ws float offsets
constexpr int WS_POOL = 64;     // 2*768
constexpr int WS_XF  = 1600;    // 2*256
constexpr int WS_PAR = 2112;    // 2*32*153 = 9792
constexpr int WS_P2  = 11904;   // 768 blocks * {sum,sumsq}

__device__ __forceinline__ float wred(float v) {
#pragma unroll
  for (int off = 32; off > 0; off >>= 1) v += __shfl_down(v, off, 64);
  return v;
}

__device__ __forceinline__ float2 fma2(float w, float2 v, float2 a) {
  a.x = fmaf(w, v.x, a.x); a.y = fmaf(w, v.y, a.y);
  return a;
}
__device__ __forceinline__ float2 relu2(float2 a) {
  a.x = fmaxf(a.x, 0.f); a.y = fmaxf(a.y, 0.f);
  return a;
}
__device__ __forceinline__ float2 bcast2(float v) { return make_float2(v, v); }

// K1: 800 blocks. Blocks 0..767: GN2 partial sums (32768 contiguous floats each).
//     Blocks 768..799: GN1 stats + relu-mean pool for one (b,group) (24576 floats).
__global__ void k1_stats(const float* __restrict__ x, const float* __restrict__ oin,
                         const float* __restrict__ g1, const float* __restrict__ b1,
                         float* __restrict__ ws) {
  int t = threadIdx.x;
  int wid = t >> 6, lane = t & 63;
  __shared__ float red[8];
  if (blockIdx.x < 768) {
    int blk = blockIdx.x;
    const float4* p = reinterpret_cast<const float4*>(oin + (size_t)blk * 32768);
    float s = 0.f, s2 = 0.f;
#pragma unroll
    for (int k = 0; k < 32; ++k) {
      float4 v = p[k * 256 + t];
      s  += v.x + v.y + v.z + v.w;
      s2 += v.x*v.x + v.y*v.y + v.z*v.z + v.w*v.w;
    }
    s = wred(s); s2 = wred(s2);
    if (lane == 0) { red[wid*2] = s; red[wid*2+1] = s2; }
    __syncthreads();
    if (t == 0) {
      ws[WS_P2 + blk*2]   = red[0]+red[2]+red[4]+red[6];
      ws[WS_P2 + blk*2+1] = red[1]+red[3]+red[5]+red[7];
    }
  } else {
    int g = blockIdx.x - 768;              // b = g>>4, grp = g&15
    __shared__ float mstat[2];
    const float4* p = reinterpret_cast<const float4*>(x + g * 24576);
    float s = 0.f, s2 = 0.f;
#pragma unroll
    for (int k = 0; k < 24; ++k) {
      float4 v = p[k * 256 + t];
      s  += v.x + v.y + v.z + v.w;
      s2 += v.x*v.x + v.y*v.y + v.z*v.z + v.w*v.w;
    }
    s = wred(s); s2 = wred(s2);
    if (lane == 0) { red[wid*2] = s; red[wid*2+1] = s2; }
    __syncthreads();
    if (t == 0) {
      float S  = red[0]+red[2]+red[4]+red[6];
      float S2 = red[1]+red[3]+red[5]+red[7];
      float mean = S * (1.f/24576.f);
      float var  = S2 * (1.f/24576.f) - mean*mean;
      mstat[0] = mean; mstat[1] = rsqrtf(var + 1e-5f);
    }
    __syncthreads();
    float mean = mstat[0], rstd = mstat[1];
#pragma unroll
    for (int k = 0; k < 12; ++k) {
      int i = k*4 + wid;                   // channel within group [0,48)
      int c = (g & 15) * 48 + i;           // channel [0,768)
      float sc = rstd * g1[c];
      float sh = b1[c] - mean * sc;
      const float* q = x + g * 24576 + i * 512;
      float acc = 0.f;
#pragma unroll
      for (int j = 0; j < 8; ++j)
        acc += fmaxf(fmaf(q[lane + j*64], sc, sh), 0.f);
      acc = wred(acc);
      if (lane == 0) ws[WS_POOL + (g >> 4) * 768 + c] = acc * (1.f/512.f);
    }
  }
}

// K2: x_feat, wave-per-output (coalesced row reads). 512 outputs -> 128 blocks.
__global__ void k2_xfeat(const float* __restrict__ gapw, const float* __restrict__ gapb,
                         float* __restrict__ ws) {
  int wid = threadIdx.x >> 6, lane = threadIdx.x & 63;
  int idx = blockIdx.x * 4 + wid;          // [0,512)
  int b = idx >> 8, o = idx & 255;
  const float* pw = gapw + o * 768;
  const float* pp = ws + WS_POOL + b * 768;
  float s = 0.f;
#pragma unroll
  for (int i = 0; i < 12; ++i) {
    int cc = lane + i*64;
    s += pw[cc] * pp[cc];
  }
  s = wred(s);
  if (lane == 0) ws[WS_XF + idx] = s + gapb[o];
}

// K3: params, wave-per-output (coalesced). 9792 outputs -> 2448 blocks.
__global__ void k3_params(const float* __restrict__ cw, const float* __restrict__ cb,
                          const float* __restrict__ te, float* __restrict__ ws) {
  int wid = threadIdx.x >> 6, lane = threadIdx.x & 63;
  int e = blockIdx.x * 4 + wid;            // [0,9792)
  int b = e / (NCLS * 153);
  int r = e % (NCLS * 153);
  int c = r / 153, p = r % 153;
  const float* w  = cw + p * 512;
  const float* xf = ws + WS_XF + b * 256;
  const float* tv = te + c * 256;
  float s = 0.f;
#pragma unroll
  for (int i = 0; i < 4; ++i) {
    int f = lane + i*64;
    s += w[f] * xf[f] + w[256 + f] * tv[f];
  }
  s = wred(s);
  if (lane == 0) ws[WS_PAR + e] = s + cb[p];
}

// K4: fused GN2-finalize + main head.
// 1024 blocks x 256 thr; thread = 2 voxels (1 float2). All 32 classes per block
// (no duplicate oin reads). Per-class weights read directly from global with
// wave-uniform indices -> backend emits s_load + SGPR-operand v_fma (off the
// DS and vector-VMEM pipes). No launch-bounds occupancy hint: natural VGPR
// (~64-96) allows the grid's 4 blocks/CU = 4 waves/SIMD without spilling.
__global__ __launch_bounds__(256) void k4_main(const float* __restrict__ oin,
                                               const float* __restrict__ prew,
                                               const float* __restrict__ preb,
                                               const float* __restrict__ g2,
                                               const float* __restrict__ b2,
                                               const float* __restrict__ ws,
                                               float* __restrict__ out) {
  __shared__ __align__(16) float prewT[384];
  __shared__ float2 ssl[48];
  __shared__ float ms[64];
  int t = threadIdx.x;
  int b    = blockIdx.x >> 9;        // batch [0,2)
  int tile = blockIdx.x & 511;       // [0,512) -> 512 voxels per channel

  if (t < 32) {
    float S = 0.f, S2 = 0.f;
#pragma unroll
    for (int k = 0; k < 24; ++k) {
      S  += ws[WS_P2 + (t*24 + k)*2];
      S2 += ws[WS_P2 + (t*24 + k)*2 + 1];
    }
    float mean = S * (1.f/786432.f);
    float var  = S2 * (1.f/786432.f) - mean*mean;
    ms[t*2] = mean; ms[t*2+1] = rsqrtf(var + 1e-5f);
  }
  if (t < 128) {
#pragma unroll
    for (int k = 0; k < 3; ++k) {
      int i = t + k*128;
      prewT[(i % 48) * 8 + (i / 48)] = prew[i];
    }
  }
  __syncthreads();
  if (t < 48) {
    int grp = (b << 4) + t / 3;
    float mean = ms[grp*2], rstd = ms[grp*2+1];
    float sc = rstd * g2[t];
    ssl[t] = make_float2(sc, b2[t] - mean * sc);
  }
  __syncthreads();

  // h0 for 2 voxels (one float2)
  const float2* ip2 = reinterpret_cast<const float2*>(oin)
                      + (size_t)b * 48 * 131072 + tile*256 + t;
  const float4* pT4 = reinterpret_cast<const float4*>(prewT);
  float2 h0[8];
#pragma unroll
  for (int o = 0; o < 8; ++o) h0[o] = bcast2(preb[o]);
#pragma unroll 8
  for (int c = 0; c < 48; ++c) {
    float2 v = ip2[(size_t)c * 131072];
    float2 ss = ssl[c];
    float2 g = relu2(make_float2(fmaf(v.x, ss.x, ss.y), fmaf(v.y, ss.x, ss.y)));
    float4 w0 = pT4[c*2], w1 = pT4[c*2+1];
    h0[0] = fma2(w0.x, g, h0[0]);
    h0[1] = fma2(w0.y, g, h0[1]);
    h0[2] = fma2(w0.z, g, h0[2]);
    h0[3] = fma2(w0.w, g, h0[3]);
    h0[4] = fma2(w1.x, g, h0[4]);
    h0[5] = fma2(w1.y, g, h0[5]);
    h0[6] = fma2(w1.z, g, h0[6]);
    h0[7] = fma2(w1.w, g, h0[7]);
  }

  // per-class head; W read with wave-uniform indices (s_load path)
  const float* __restrict__ Wb = ws + WS_PAR + (size_t)b * NCLS * 153;
  float2* op2 = reinterpret_cast<float2*>(out)
                + (size_t)b * NCLS * 131072 + tile*256 + t;
#pragma unroll 1
  for (int cls = 0; cls < NCLS; ++cls) {
    const float* Wc = Wb + cls * 153;
    // layer1: t1 = relu(w1 @ h0 + b1)
    float2 t1[8];
#pragma unroll
    for (int i = 0; i < 8; ++i) {
      float2 a = bcast2(Wc[136 + i]);
#pragma unroll
      for (int j = 0; j < 8; ++j) a = fma2(Wc[i*8 + j], h0[j], a);
      t1[i] = relu2(a);
    }
    // layer2 + layer3 fused
    float2 lg = bcast2(Wc[152]);
#pragma unroll
    for (int i = 0; i < 8; ++i) {
      float2 a = bcast2(Wc[144 + i]);
#pragma unroll
      for (int j = 0; j < 8; ++j) a = fma2(Wc[64 + i*8 + j], t1[j], a);
      a = relu2(a);
      lg = fma2(Wc[128 + i], a, lg);
    }
    op2[(size_t)cls * 131072] = lg;
  }
}

extern "C" void kernel_launch(void* const* d_in, const int* in_sizes, int n_in,
                              void* d_out, int out_size, void* d_ws, size_t ws_size,
                              hipStream_t stream) {
  const float* x    = (const float*)d_in[0];
  const float* oin  = (const float*)d_in[1];
  const float* te   = (const float*)d_in[2];
  const float* g1   = (const float*)d_in[3];
  const float* b1   = (const float*)d_in[4];
  const float* gapw = (const float*)d_in[5];
  const float* gapb = (const float*)d_in[6];
  const float* cw   = (const float*)d_in[7];
  const float* cb   = (const float*)d_in[8];
  const float* g2   = (const float*)d_in[9];
  const float* b2   = (const float*)d_in[10];
  const float* prew = (const float*)d_in[11];
  const float* preb = (const float*)d_in[12];
  float* ws  = (float*)d_ws;
  float* out = (float*)d_out;

  hipLaunchKernelGGL(k1_stats,  dim3(800),  dim3(256), 0, stream, x, oin, g1, b1, ws);
  hipLaunchKernelGGL(k2_xfeat,  dim3(128),  dim3(256), 0, stream, gapw, gapb, ws);
  hipLaunchKernelGGL(k3_params, dim3(2448), dim3(256), 0, stream, cw, cb, te, ws);
  hipLaunchKernelGGL(k4_main,   dim3(1024), dim3(256), 0, stream, oin, prew, preb, g2, b2, ws, out);
}

// Round 3
// 281.752 us; speedup vs baseline: 1.4485x; 1.1790x over previous
//
#include <hip/hip_runtime.h>

// x:    (2, 768, 8,8,8)   -> (2,768,512)
// out:  (2, 48, 64,64,64) -> (2,48,262144)
// output: (2, 32, 64,64,64)
constexpr int NCLS = 32;

// ws float offsets
constexpr int WS_POOL = 64;     // 2*768
constexpr int WS_XF  = 1600;    // 2*256
constexpr int WS_PAR = 2112;    // 2*32*153 = 9792
constexpr int WS_P2  = 11904;   // 768 blocks * {sum,sumsq}

typedef float f2 __attribute__((ext_vector_type(2)));

__device__ __forceinline__ float wred(float v) {
#pragma unroll
  for (int off = 32; off > 0; off >>= 1) v += __shfl_down(v, off, 64);
  return v;
}

// packed fp32 helpers -> v_pk_fma_f32 / v_max_f32 pairs
__device__ __forceinline__ f2 pfma(float w, f2 v, f2 a) {
  return __builtin_elementwise_fma((f2)w, v, a);
}
__device__ __forceinline__ f2 paff(f2 v, float sc, float sh) {
  return __builtin_elementwise_fma(v, (f2)sc, (f2)sh);
}
__device__ __forceinline__ f2 prelu(f2 a) {
  return __builtin_elementwise_max(a, (f2)0.f);
}

// K1: 800 blocks. Blocks 0..767: GN2 partial sums (32768 contiguous floats each).
//     Blocks 768..799: GN1 stats + relu-mean pool for one (b,group) (24576 floats).
__global__ void k1_stats(const float* __restrict__ x, const float* __restrict__ oin,
                         const float* __restrict__ g1, const float* __restrict__ b1,
                         float* __restrict__ ws) {
  int t = threadIdx.x;
  int wid = t >> 6, lane = t & 63;
  __shared__ float red[8];
  if (blockIdx.x < 768) {
    int blk = blockIdx.x;
    const float4* p = reinterpret_cast<const float4*>(oin + (size_t)blk * 32768);
    float s = 0.f, s2 = 0.f;
#pragma unroll
    for (int k = 0; k < 32; ++k) {
      float4 v = p[k * 256 + t];
      s  += v.x + v.y + v.z + v.w;
      s2 += v.x*v.x + v.y*v.y + v.z*v.z + v.w*v.w;
    }
    s = wred(s); s2 = wred(s2);
    if (lane == 0) { red[wid*2] = s; red[wid*2+1] = s2; }
    __syncthreads();
    if (t == 0) {
      ws[WS_P2 + blk*2]   = red[0]+red[2]+red[4]+red[6];
      ws[WS_P2 + blk*2+1] = red[1]+red[3]+red[5]+red[7];
    }
  } else {
    int g = blockIdx.x - 768;              // b = g>>4, grp = g&15
    __shared__ float mstat[2];
    const float4* p = reinterpret_cast<const float4*>(x + g * 24576);
    float s = 0.f, s2 = 0.f;
#pragma unroll
    for (int k = 0; k < 24; ++k) {
      float4 v = p[k * 256 + t];
      s  += v.x + v.y + v.z + v.w;
      s2 += v.x*v.x + v.y*v.y + v.z*v.z + v.w*v.w;
    }
    s = wred(s); s2 = wred(s2);
    if (lane == 0) { red[wid*2] = s; red[wid*2+1] = s2; }
    __syncthreads();
    if (t == 0) {
      float S  = red[0]+red[2]+red[4]+red[6];
      float S2 = red[1]+red[3]+red[5]+red[7];
      float mean = S * (1.f/24576.f);
      float var  = S2 * (1.f/24576.f) - mean*mean;
      mstat[0] = mean; mstat[1] = rsqrtf(var + 1e-5f);
    }
    __syncthreads();
    float mean = mstat[0], rstd = mstat[1];
#pragma unroll
    for (int k = 0; k < 12; ++k) {
      int i = k*4 + wid;                   // channel within group [0,48)
      int c = (g & 15) * 48 + i;           // channel [0,768)
      float sc = rstd * g1[c];
      float sh = b1[c] - mean * sc;
      const float* q = x + g * 24576 + i * 512;
      float acc = 0.f;
#pragma unroll
      for (int j = 0; j < 8; ++j)
        acc += fmaxf(fmaf(q[lane + j*64], sc, sh), 0.f);
      acc = wred(acc);
      if (lane == 0) ws[WS_POOL + (g >> 4) * 768 + c] = acc * (1.f/512.f);
    }
  }
}

// K2: x_feat, wave-per-output (coalesced row reads). 512 outputs -> 128 blocks.
__global__ void k2_xfeat(const float* __restrict__ gapw, const float* __restrict__ gapb,
                         float* __restrict__ ws) {
  int wid = threadIdx.x >> 6, lane = threadIdx.x & 63;
  int idx = blockIdx.x * 4 + wid;          // [0,512)
  int b = idx >> 8, o = idx & 255;
  const float* pw = gapw + o * 768;
  const float* pp = ws + WS_POOL + b * 768;
  float s = 0.f;
#pragma unroll
  for (int i = 0; i < 12; ++i) {
    int cc = lane + i*64;
    s += pw[cc] * pp[cc];
  }
  s = wred(s);
  if (lane == 0) ws[WS_XF + idx] = s + gapb[o];
}

// K3: params, wave-per-output (coalesced). 9792 outputs -> 2448 blocks.
__global__ void k3_params(const float* __restrict__ cw, const float* __restrict__ cb,
                          const float* __restrict__ te, float* __restrict__ ws) {
  int wid = threadIdx.x >> 6, lane = threadIdx.x & 63;
  int e = blockIdx.x * 4 + wid;            // [0,9792)
  int b = e / (NCLS * 153);
  int r = e % (NCLS * 153);
  int c = r / 153, p = r % 153;
  const float* w  = cw + p * 512;
  const float* xf = ws + WS_XF + b * 256;
  const float* tv = te + c * 256;
  float s = 0.f;
#pragma unroll
  for (int i = 0; i < 4; ++i) {
    int f = lane + i*64;
    s += w[f] * xf[f] + w[256 + f] * tv[f];
  }
  s = wred(s);
  if (lane == 0) ws[WS_PAR + e] = s + cb[p];
}

// K4: fused GN2-finalize + main head.
// 512 blocks x 256 thr; thread = 8 voxels (4 x f2 packed pairs) — keeps round-0's
// per-wave weight amortization (512 voxels/wave/class). Classes split 16/16 across
// paired blocks -> 2 blocks/CU = 2 waves/SIMD (VGPR ~228 allows 2). Math in packed
// fp32 (v_pk_fma_f32) to halve VALU issue. Weights staged in LDS as in round 0.
__global__ __launch_bounds__(256) void k4_main(const float* __restrict__ oin,
                                               const float* __restrict__ prew,
                                               const float* __restrict__ preb,
                                               const float* __restrict__ g2,
                                               const float* __restrict__ b2,
                                               const float* __restrict__ ws,
                                               float* __restrict__ out) {
  __shared__ __align__(16) float Wl[16 * 160];
  __shared__ __align__(16) float prewT[384];
  __shared__ float2 ssl[48];
  __shared__ float ms[64];
  int t = threadIdx.x;
  int b    = blockIdx.x >> 8;        // batch [0,2)
  int rem  = blockIdx.x & 255;
  int tile = rem >> 1;               // [0,128) -> 2048 voxels per tile
  int cls0 = (rem & 1) << 4;         // 0 or 16

  if (t < 32) {
    float S = 0.f, S2 = 0.f;
#pragma unroll
    for (int k = 0; k < 24; ++k) {
      S  += ws[WS_P2 + (t*24 + k)*2];
      S2 += ws[WS_P2 + (t*24 + k)*2 + 1];
    }
    float mean = S * (1.f/786432.f);
    float var  = S2 * (1.f/786432.f) - mean*mean;
    ms[t*2] = mean; ms[t*2+1] = rsqrtf(var + 1e-5f);
  }
  if (t < 128) {
#pragma unroll
    for (int k = 0; k < 3; ++k) {
      int i = t + k*128;
      prewT[(i % 48) * 8 + (i / 48)] = prew[i];
    }
  }
  {
    const float* wsrc = ws + WS_PAR + (size_t)(b * NCLS + cls0) * 153;
#pragma unroll 4
    for (int cc = 0; cc < 16; ++cc)
      if (t < 153) Wl[cc*160 + t] = wsrc[cc*153 + t];
  }
  __syncthreads();
  if (t < 48) {
    int grp = (b << 4) + t / 3;
    float mean = ms[grp*2], rstd = ms[grp*2+1];
    float sc = rstd * g2[t];
    ssl[t] = make_float2(sc, b2[t] - mean * sc);
  }
  __syncthreads();

  // h0 for 8 voxels: two float4 groups (at +0 and +256 float4s), held as 4 f2 pairs.
  const float4* ip4 = reinterpret_cast<const float4*>(oin)
                      + (size_t)b * 48 * 65536 + tile*512 + t;
  const float4* pT4 = reinterpret_cast<const float4*>(prewT);
  f2 h0[8][4];
#pragma unroll
  for (int o = 0; o < 8; ++o) {
    float pb = preb[o];
#pragma unroll
    for (int p = 0; p < 4; ++p) h0[o][p] = (f2)pb;
  }
#pragma unroll 8
  for (int c = 0; c < 48; ++c) {
    float4 va = ip4[(size_t)c * 65536];
    float4 vb = ip4[(size_t)c * 65536 + 256];
    float2 ss = ssl[c];
    f2 g[4];
    g[0] = prelu(paff((f2){va.x, va.y}, ss.x, ss.y));
    g[1] = prelu(paff((f2){va.z, va.w}, ss.x, ss.y));
    g[2] = prelu(paff((f2){vb.x, vb.y}, ss.x, ss.y));
    g[3] = prelu(paff((f2){vb.z, vb.w}, ss.x, ss.y));
    float4 w0 = pT4[c*2], w1 = pT4[c*2+1];
    float wv[8] = {w0.x, w0.y, w0.z, w0.w, w1.x, w1.y, w1.z, w1.w};
#pragma unroll
    for (int o = 0; o < 8; ++o)
#pragma unroll
      for (int p = 0; p < 4; ++p) h0[o][p] = pfma(wv[o], g[p], h0[o][p]);
  }

  float4* op4 = reinterpret_cast<float4*>(out)
                + (size_t)(b * NCLS + cls0) * 65536 + tile*512 + t;
#pragma unroll 1
  for (int cls = 0; cls < 16; ++cls) {
    const float*  Wc = Wl + cls * 160;
    const float4* W4 = reinterpret_cast<const float4*>(Wc);
    float4 b1q0 = W4[34], b1q1 = W4[35];     // b1[0..7]
    float4 b2q0 = W4[36], b2q1 = W4[37];     // b2[0..7]
    float4 w3q0 = W4[32], w3q1 = W4[33];     // w3[0..7]
    float b3v = Wc[152];
    float b1arr[8] = {b1q0.x,b1q0.y,b1q0.z,b1q0.w,b1q1.x,b1q1.y,b1q1.z,b1q1.w};
    float b2arr[8] = {b2q0.x,b2q0.y,b2q0.z,b2q0.w,b2q1.x,b2q1.y,b2q1.z,b2q1.w};
    float w3arr[8] = {w3q0.x,w3q0.y,w3q0.z,w3q0.w,w3q1.x,w3q1.y,w3q1.z,w3q1.w};

    // layer1: t1 = relu(w1 @ h0 + b1)
    f2 t1[8][4];
#pragma unroll
    for (int i = 0; i < 8; ++i) {
      float4 w0 = W4[i*2], w1 = W4[i*2+1];
      float wv[8] = {w0.x, w0.y, w0.z, w0.w, w1.x, w1.y, w1.z, w1.w};
      f2 a[4];
#pragma unroll
      for (int p = 0; p < 4; ++p) a[p] = (f2)b1arr[i];
#pragma unroll
      for (int j = 0; j < 8; ++j)
#pragma unroll
        for (int p = 0; p < 4; ++p) a[p] = pfma(wv[j], h0[j][p], a[p]);
#pragma unroll
      for (int p = 0; p < 4; ++p) t1[i][p] = prelu(a[p]);
    }
    // layer2 + layer3 fused (t2 row consumed immediately)
    f2 lg[4];
#pragma unroll
    for (int p = 0; p < 4; ++p) lg[p] = (f2)b3v;
#pragma unroll
    for (int i = 0; i < 8; ++i) {
      float4 w0 = W4[16 + i*2], w1 = W4[17 + i*2];
      float wv[8] = {w0.x, w0.y, w0.z, w0.w, w1.x, w1.y, w1.z, w1.w};
      f2 a[4];
#pragma unroll
      for (int p = 0; p < 4; ++p) a[p] = (f2)b2arr[i];
#pragma unroll
      for (int j = 0; j < 8; ++j)
#pragma unroll
        for (int p = 0; p < 4; ++p) a[p] = pfma(wv[j], t1[j][p], a[p]);
#pragma unroll
      for (int p = 0; p < 4; ++p) {
        a[p] = prelu(a[p]);
        lg[p] = pfma(w3arr[i], a[p], lg[p]);
      }
    }
    op4[(size_t)cls * 65536]       = make_float4(lg[0].x, lg[0].y, lg[1].x, lg[1].y);
    op4[(size_t)cls * 65536 + 256] = make_float4(lg[2].x, lg[2].y, lg[3].x, lg[3].y);
  }
}

extern "C" void kernel_launch(void* const* d_in, const int* in_sizes, int n_in,
                              void* d_out, int out_size, void* d_ws, size_t ws_size,
                              hipStream_t stream) {
  const float* x    = (const float*)d_in[0];
  const float* oin  = (const float*)d_in[1];
  const float* te   = (const float*)d_in[2];
  const float* g1   = (const float*)d_in[3];
  const float* b1   = (const float*)d_in[4];
  const float* gapw = (const float*)d_in[5];
  const float* gapb = (const float*)d_in[6];
  const float* cw   = (const float*)d_in[7];
  const float* cb   = (const float*)d_in[8];
  const float* g2   = (const float*)d_in[9];
  const float* b2   = (const float*)d_in[10];
  const float* prew = (const float*)d_in[11];
  const float* preb = (const float*)d_in[12];
  float* ws  = (float*)d_ws;
  float* out = (float*)d_out;

  hipLaunchKernelGGL(k1_stats,  dim3(800),  dim3(256), 0, stream, x, oin, g1, b1, ws);
  hipLaunchKernelGGL(k2_xfeat,  dim3(128),  dim3(256), 0, stream, gapw, gapb, ws);
  hipLaunchKernelGGL(k3_params, dim3(2448), dim3(256), 0, stream, cw, cb, te, ws);
  hipLaunchKernelGGL(k4_main,   dim3(512),  dim3(256), 0, stream, oin, prew, preb, g2, b2, ws, out);
}

// Round 4
// 270.175 us; speedup vs baseline: 1.5106x; 1.0429x over previous
//
#include <hip/hip_runtime.h>

// x:    (2, 768, 8,8,8)   -> (2,768,512)
// out:  (2, 48, 64,64,64) -> (2,48,262144)
// output: (2, 32, 64,64,64)
constexpr int NCLS = 32;

// ws float offsets
constexpr int WS_POOL = 64;     // 2*768
constexpr int WS_XF  = 1600;    // 2*256
constexpr int WS_PAR = 2112;    // 2*32*153 = 9792
constexpr int WS_P2  = 11904;   // 768 blocks * {sum,sumsq}

typedef float f2 __attribute__((ext_vector_type(2)));

__device__ __forceinline__ float wred(float v) {
#pragma unroll
  for (int off = 32; off > 0; off >>= 1) v += __shfl_down(v, off, 64);
  return v;
}

// packed fp32 helpers -> v_pk_fma_f32 / v_pk_max_f32 (full dual-rate on CDNA4,
// verified round 3: VALU issue matched the 2-MAC/instr model)
__device__ __forceinline__ f2 pfma(float w, f2 v, f2 a) {
  return __builtin_elementwise_fma((f2)w, v, a);
}
__device__ __forceinline__ f2 paff(f2 v, float sc, float sh) {
  return __builtin_elementwise_fma(v, (f2)sc, (f2)sh);
}
__device__ __forceinline__ f2 prelu(f2 a) {
  return __builtin_elementwise_max(a, (f2)0.f);
}

// K1: 800 blocks. Blocks 0..767: GN2 partial sums (32768 contiguous floats each).
//     Blocks 768..799: GN1 stats + relu-mean pool for one (b,group) (24576 floats).
__global__ void k1_stats(const float* __restrict__ x, const float* __restrict__ oin,
                         const float* __restrict__ g1, const float* __restrict__ b1,
                         float* __restrict__ ws) {
  int t = threadIdx.x;
  int wid = t >> 6, lane = t & 63;
  __shared__ float red[8];
  if (blockIdx.x < 768) {
    int blk = blockIdx.x;
    const float4* p = reinterpret_cast<const float4*>(oin + (size_t)blk * 32768);
    float s = 0.f, s2 = 0.f;
#pragma unroll
    for (int k = 0; k < 32; ++k) {
      float4 v = p[k * 256 + t];
      s  += v.x + v.y + v.z + v.w;
      s2 += v.x*v.x + v.y*v.y + v.z*v.z + v.w*v.w;
    }
    s = wred(s); s2 = wred(s2);
    if (lane == 0) { red[wid*2] = s; red[wid*2+1] = s2; }
    __syncthreads();
    if (t == 0) {
      ws[WS_P2 + blk*2]   = red[0]+red[2]+red[4]+red[6];
      ws[WS_P2 + blk*2+1] = red[1]+red[3]+red[5]+red[7];
    }
  } else {
    int g = blockIdx.x - 768;              // b = g>>4, grp = g&15
    __shared__ float mstat[2];
    const float4* p = reinterpret_cast<const float4*>(x + g * 24576);
    float s = 0.f, s2 = 0.f;
#pragma unroll
    for (int k = 0; k < 24; ++k) {
      float4 v = p[k * 256 + t];
      s  += v.x + v.y + v.z + v.w;
      s2 += v.x*v.x + v.y*v.y + v.z*v.z + v.w*v.w;
    }
    s = wred(s); s2 = wred(s2);
    if (lane == 0) { red[wid*2] = s; red[wid*2+1] = s2; }
    __syncthreads();
    if (t == 0) {
      float S  = red[0]+red[2]+red[4]+red[6];
      float S2 = red[1]+red[3]+red[5]+red[7];
      float mean = S * (1.f/24576.f);
      float var  = S2 * (1.f/24576.f) - mean*mean;
      mstat[0] = mean; mstat[1] = rsqrtf(var + 1e-5f);
    }
    __syncthreads();
    float mean = mstat[0], rstd = mstat[1];
#pragma unroll
    for (int k = 0; k < 12; ++k) {
      int i = k*4 + wid;                   // channel within group [0,48)
      int c = (g & 15) * 48 + i;           // channel [0,768)
      float sc = rstd * g1[c];
      float sh = b1[c] - mean * sc;
      const float* q = x + g * 24576 + i * 512;
      float acc = 0.f;
#pragma unroll
      for (int j = 0; j < 8; ++j)
        acc += fmaxf(fmaf(q[lane + j*64], sc, sh), 0.f);
      acc = wred(acc);
      if (lane == 0) ws[WS_POOL + (g >> 4) * 768 + c] = acc * (1.f/512.f);
    }
  }
}

// K2: x_feat, wave-per-output (coalesced row reads). 512 outputs -> 128 blocks.
__global__ void k2_xfeat(const float* __restrict__ gapw, const float* __restrict__ gapb,
                         float* __restrict__ ws) {
  int wid = threadIdx.x >> 6, lane = threadIdx.x & 63;
  int idx = blockIdx.x * 4 + wid;          // [0,512)
  int b = idx >> 8, o = idx & 255;
  const float* pw = gapw + o * 768;
  const float* pp = ws + WS_POOL + b * 768;
  float s = 0.f;
#pragma unroll
  for (int i = 0; i < 12; ++i) {
    int cc = lane + i*64;
    s += pw[cc] * pp[cc];
  }
  s = wred(s);
  if (lane == 0) ws[WS_XF + idx] = s + gapb[o];
}

// K3: params, wave-per-output (coalesced). 9792 outputs -> 2448 blocks.
__global__ void k3_params(const float* __restrict__ cw, const float* __restrict__ cb,
                          const float* __restrict__ te, float* __restrict__ ws) {
  int wid = threadIdx.x >> 6, lane = threadIdx.x & 63;
  int e = blockIdx.x * 4 + wid;            // [0,9792)
  int b = e / (NCLS * 153);
  int r = e % (NCLS * 153);
  int c = r / 153, p = r % 153;
  const float* w  = cw + p * 512;
  const float* xf = ws + WS_XF + b * 256;
  const float* tv = te + c * 256;
  float s = 0.f;
#pragma unroll
  for (int i = 0; i < 4; ++i) {
    int f = lane + i*64;
    s += w[f] * xf[f] + w[256 + f] * tv[f];
  }
  s = wred(s);
  if (lane == 0) ws[WS_PAR + e] = s + cb[p];
}

// K4: fused GN2-finalize + main head. v4 synthesis:
//  - 512 blocks x 256 thr; thread = 4 voxels (1 float4 = 2 f2). ALL 32 classes
//    per block: zero h0 duplication, single oin pass (round-3's split cost 9%
//    issue + 49 MB HBM).
//  - weights via wave-uniform global reads -> s_load + SGPR-operand v_pk_fma
//    (round 2 proved this path: SGPR 112, best VALUBusy/stall profile; removes
//    the 608 ds_reads/wave LDS dependency of rounds 0/3).
//  - packed fp32 math throughout (round 3 proved full dual-rate).
//  State = h0[8][2] + t1[8][2] = 64 VGPRs -> ~100-110 total, 2 blocks/CU.
__global__ __launch_bounds__(256) void k4_main(const float* __restrict__ oin,
                                               const float* __restrict__ prew,
                                               const float* __restrict__ preb,
                                               const float* __restrict__ g2,
                                               const float* __restrict__ b2,
                                               const float* __restrict__ ws,
                                               float* __restrict__ out) {
  __shared__ __align__(16) float prewT[384];
  __shared__ float2 ssl[48];
  __shared__ float ms[64];
  int t = threadIdx.x;
  int b    = blockIdx.x >> 8;        // batch [0,2)
  int tile = blockIdx.x & 255;       // [0,256) -> 1024 voxels per tile

  if (t < 32) {
    float S = 0.f, S2 = 0.f;
#pragma unroll
    for (int k = 0; k < 24; ++k) {
      S  += ws[WS_P2 + (t*24 + k)*2];
      S2 += ws[WS_P2 + (t*24 + k)*2 + 1];
    }
    float mean = S * (1.f/786432.f);
    float var  = S2 * (1.f/786432.f) - mean*mean;
    ms[t*2] = mean; ms[t*2+1] = rsqrtf(var + 1e-5f);
  }
  if (t < 128) {
#pragma unroll
    for (int k = 0; k < 3; ++k) {
      int i = t + k*128;
      prewT[(i % 48) * 8 + (i / 48)] = prew[i];
    }
  }
  __syncthreads();
  if (t < 48) {
    int grp = (b << 4) + t / 3;
    float mean = ms[grp*2], rstd = ms[grp*2+1];
    float sc = rstd * g2[t];
    ssl[t] = make_float2(sc, b2[t] - mean * sc);
  }
  __syncthreads();

  // h0 for 4 voxels (one float4 = 2 f2)
  const float4* ip4 = reinterpret_cast<const float4*>(oin)
                      + (size_t)b * 48 * 65536 + tile*256 + t;
  const float4* pT4 = reinterpret_cast<const float4*>(prewT);
  f2 h0[8][2];
#pragma unroll
  for (int o = 0; o < 8; ++o) {
    float pb = preb[o];
    h0[o][0] = (f2)pb; h0[o][1] = (f2)pb;
  }
#pragma unroll 8
  for (int c = 0; c < 48; ++c) {
    float4 v = ip4[(size_t)c * 65536];
    float2 ss = ssl[c];
    f2 g0 = prelu(paff((f2){v.x, v.y}, ss.x, ss.y));
    f2 g1 = prelu(paff((f2){v.z, v.w}, ss.x, ss.y));
    float4 w0 = pT4[c*2], w1 = pT4[c*2+1];
    float wv[8] = {w0.x, w0.y, w0.z, w0.w, w1.x, w1.y, w1.z, w1.w};
#pragma unroll
    for (int o = 0; o < 8; ++o) {
      h0[o][0] = pfma(wv[o], g0, h0[o][0]);
      h0[o][1] = pfma(wv[o], g1, h0[o][1]);
    }
  }

  // per-class head; W read with wave-uniform indices (s_load path)
  const float* __restrict__ Wb = ws + WS_PAR + (size_t)b * NCLS * 153;
  float4* op4 = reinterpret_cast<float4*>(out)
                + (size_t)b * NCLS * 65536 + tile*256 + t;
#pragma unroll 1
  for (int cls = 0; cls < NCLS; ++cls) {
    const float* Wc = Wb + cls * 153;
    // layer1: t1 = relu(w1 @ h0 + b1)
    f2 t1[8][2];
#pragma unroll
    for (int i = 0; i < 8; ++i) {
      float bi = Wc[136 + i];
      f2 a0 = (f2)bi, a1 = (f2)bi;
#pragma unroll
      for (int j = 0; j < 8; ++j) {
        float w = Wc[i*8 + j];
        a0 = pfma(w, h0[j][0], a0);
        a1 = pfma(w, h0[j][1], a1);
      }
      t1[i][0] = prelu(a0); t1[i][1] = prelu(a1);
    }
    // layer2 + layer3 fused (t2 row consumed immediately)
    float b3v = Wc[152];
    f2 lg0 = (f2)b3v, lg1 = (f2)b3v;
#pragma unroll
    for (int i = 0; i < 8; ++i) {
      float bi = Wc[144 + i];
      f2 a0 = (f2)bi, a1 = (f2)bi;
#pragma unroll
      for (int j = 0; j < 8; ++j) {
        float w = Wc[64 + i*8 + j];
        a0 = pfma(w, t1[j][0], a0);
        a1 = pfma(w, t1[j][1], a1);
      }
      a0 = prelu(a0); a1 = prelu(a1);
      float w3 = Wc[128 + i];
      lg0 = pfma(w3, a0, lg0);
      lg1 = pfma(w3, a1, lg1);
    }
    op4[(size_t)cls * 65536] = make_float4(lg0.x, lg0.y, lg1.x, lg1.y);
  }
}

extern "C" void kernel_launch(void* const* d_in, const int* in_sizes, int n_in,
                              void* d_out, int out_size, void* d_ws, size_t ws_size,
                              hipStream_t stream) {
  const float* x    = (const float*)d_in[0];
  const float* oin  = (const float*)d_in[1];
  const float* te   = (const float*)d_in[2];
  const float* g1   = (const float*)d_in[3];
  const float* b1   = (const float*)d_in[4];
  const float* gapw = (const float*)d_in[5];
  const float* gapb = (const float*)d_in[6];
  const float* cw   = (const float*)d_in[7];
  const float* cb   = (const float*)d_in[8];
  const float* g2   = (const float*)d_in[9];
  const float* b2   = (const float*)d_in[10];
  const float* prew = (const float*)d_in[11];
  const float* preb = (const float*)d_in[12];
  float* ws  = (float*)d_ws;
  float* out = (float*)d_out;

  hipLaunchKernelGGL(k1_stats,  dim3(800),  dim3(256), 0, stream, x, oin, g1, b1, ws);
  hipLaunchKernelGGL(k2_xfeat,  dim3(128),  dim3(256), 0, stream, gapw, gapb, ws);
  hipLaunchKernelGGL(k3_params, dim3(2448), dim3(256), 0, stream, cw, cb, te, ws);
  hipLaunchKernelGGL(k4_main,   dim3(512),  dim3(256), 0, stream, oin, prew, preb, g2, b2, ws, out);
}